// Round 18
// baseline (581.299 us; speedup 1.0000x reference)
//
#include <hip/hip_runtime.h>
#include <hip/hip_bf16.h>

#define N_B 32
#define M_O 20
#define C_C 512
#define S_S 196
#define S_P 208
#define K_K 3920
#define K_P 4096
#define SCALEF 0.044194173824159216f  // 1/sqrt(512)

typedef short s4v __attribute__((ext_vector_type(4)));
typedef short s8v __attribute__((ext_vector_type(8)));
typedef float f4v __attribute__((ext_vector_type(4)));

__device__ __forceinline__ f4v mfma16(s8v a, s8v b, f4v c){
  return __builtin_amdgcn_mfma_f32_16x16x32_bf16(a, b, c, 0, 0, 0);
}
__device__ __forceinline__ unsigned short f2b(float x){
  __hip_bfloat16 h = __float2bfloat16(x);
  return *reinterpret_cast<unsigned short*>(&h);
}
__device__ __forceinline__ float b2f(short u){
  unsigned int v = ((unsigned int)(unsigned short)u) << 16;
  return __uint_as_float(v);
}

#define GLOAD16(g, l) __builtin_amdgcn_global_load_lds( \
    (const __attribute__((address_space(1))) unsigned int*)(g), \
    (__attribute__((address_space(3))) unsigned int*)(l), 16, 0, 0)

__global__ void k_sentinel(float* out, float v){ out[threadIdx.x] = v; }

__global__ void k_cvt(const float* __restrict__ w0, const float* __restrict__ w1,
                      const float* __restrict__ w2, const float* __restrict__ w3,
                      unsigned short* __restrict__ out){
  int i = blockIdx.x*256 + threadIdx.x;
  int m = i >> 16;
  int r = i & 65535;
  const float* s = (m==0)?w0:((m==1)?w1:((m==2)?w2:w3));
  f4v v = ((const f4v*)s)[r];
  s4v o = { (short)f2b(v[0]), (short)f2b(v[1]), (short)f2b(v[2]), (short)f2b(v[3]) };
  ((s4v*)out)[i] = o;
}

// Transpose+cvt: X fp32 [slab][512][196] -> Xt bf16 [slab][196][512]
__global__ __launch_bounds__(256) void k_tr(const float* __restrict__ X,
                                            unsigned short* __restrict__ Xt){
  const int cc = blockIdx.x * 64;
  const int slab = blockIdx.y;
  const int tid = threadIdx.x;
  __shared__ unsigned short A[196][72];
  const int row = tid >> 2;
  const int j   = tid & 3;
  const float* src = X + (size_t)slab*(C_C*S_S) + (size_t)(cc+row)*S_S;
  for (int p = j; p < 49; p += 4){
    f4v v = *(const f4v*)(src + p*4);
    int s = p*4;
    A[s+0][row] = f2b(v[0]);
    A[s+1][row] = f2b(v[1]);
    A[s+2][row] = f2b(v[2]);
    A[s+3][row] = f2b(v[3]);
  }
  __syncthreads();
  unsigned short* dst = Xt + (size_t)slab*(S_S*C_C) + cc;
  for (int v = tid; v < S_S*8; v += 256){
    int s = v >> 3, c8 = v & 7;
    *(s8v*)(dst + (size_t)s*C_C + c8*8) = *(const s8v*)&A[s][c8*8];
  }
}

// ---------------------------------------------------------------------------
// Projection GEMM, T3/T4/T5 phased schedule (r17) WITHOUT the scheduler pin:
// no manual lgkmcnt(0)/sched_barrier(0) — compiler inserts fine-grained
// lgkmcnt between ds_read and MFMA (m141: pinning costs ~40%). Per phase:
// STAGE next-step gloads FIRST (T3 recipe), then ds_read half h, counted
// vmcnt(5) (never 0 mid-loop), barrier, setprio(1) MFMA setprio(0), barrier.
// BK=64 = 2 phases/step, 16 MFMA/phase. 256 threads = 4 waves, tile 64x256,
// contiguous-64B staging + T2 swizzle.
// Waves 0-1: K output; waves 2-3: V output (swapped-operand, transposed store).
// ---------------------------------------------------------------------------
template<bool HASV>
__global__ __launch_bounds__(256, 2) void k_projgemm(
    const unsigned short* __restrict__ Xt,
    const unsigned short* __restrict__ W1, const float* __restrict__ b1, const float* __restrict__ pos1,
    const unsigned short* __restrict__ W2, const float* __restrict__ b2, const float* __restrict__ pos2,
    unsigned short* __restrict__ outK, unsigned short* __restrict__ outVT)
{
  const int id = blockIdx.x;
  const int work = HASV ? ((id & 7)*980 + (id >> 3)) : id;
  const int ct    = HASV ? (work & 3) : (work & 1);
  const int rtile = HASV ? (work >> 2) : (work >> 1);
  const int r0 = rtile*64;
  const int cb = ct * (HASV ? 128 : 256);
  const int tid = threadIdx.x, wid = tid>>6, lane = tid&63;
  const int lr = lane&15, lq = lane>>4;
  const int mat = wid >> 1, chalf = (wid & 1)*64;
  const bool isV = HASV && (mat == 1);

  const unsigned short* WB = HASV ? W2 : W1;
  const int cbB = HASV ? cb : cb + 128;

  __shared__ unsigned short SA[2][2][2048];   // [buf][h][row*32+c] 64x32
  __shared__ unsigned short SB[2][2][8192];   // [buf][h][brow*32+c] 256x32

  f4v acc[4][4];
  #pragma unroll
  for (int i=0;i<4;i++)
    #pragma unroll
    for (int j=0;j<4;j++) acc[i][j]=(f4v){0,0,0,0};

  const int rsub = lane >> 2;
  const int csub = ((lane & 3) ^ ((rsub>>1)&3)) * 8;

  auto STAGE = [&](int buf, int h, int c0){
    const unsigned short* ga = Xt + (size_t)(r0 + wid*16 + rsub)*C_C + c0 + h*32 + csub;
    GLOAD16(ga, &SA[buf][h][(wid*16)*32]);
    #pragma unroll
    for (int j=0;j<4;j++){
      const int br = j*64 + wid*16 + rsub;
      const unsigned short* gw = (j<2)
        ? W1 + (size_t)(cb  + br      )*C_C + c0 + h*32 + csub
        : WB + (size_t)(cbB + br - 128)*C_C + c0 + h*32 + csub;
      GLOAD16(gw, &SB[buf][h][(j*64 + wid*16)*32]);
    }
  };

  STAGE(0, 0, 0);
  STAGE(0, 1, 0);
  asm volatile("s_waitcnt vmcnt(5)" ::: "memory");   // (0,0) ready; (0,1) in flight
  __builtin_amdgcn_s_barrier();

  const int bbase = mat*128 + chalf;
  const int rchunk = (lq ^ ((lr>>1)&3)) * 8;
  for (int it = 0; it < 8; ++it){
    const int buf = it & 1;
    #pragma unroll
    for (int h = 0; h < 2; ++h){
      if (it < 7) STAGE(buf^1, h, (it+1)*64);   // issue-first (T3)
      s8v af[4], bf[4];
      #pragma unroll
      for (int i=0;i<4;i++)
        af[i] = *(const s8v*)&SA[buf][h][(i*16 + lr)*32 + rchunk];
      #pragma unroll
      for (int i=0;i<4;i++)
        bf[i] = *(const s8v*)&SB[buf][h][(bbase + i*16 + lr)*32 + rchunk];
      if (it < 7){
        asm volatile("s_waitcnt vmcnt(5)" ::: "memory");
      } else {
        asm volatile("s_waitcnt vmcnt(0)" ::: "memory");
      }
      __builtin_amdgcn_s_barrier();
      __builtin_amdgcn_s_setprio(1);
      if (!isV){
        #pragma unroll
        for (int ot=0;ot<4;ot++)
          #pragma unroll
          for (int rt=0;rt<4;rt++)
            acc[rt][ot] = mfma16(af[rt], bf[ot], acc[rt][ot]);
      } else {
        #pragma unroll
        for (int ot=0;ot<4;ot++)
          #pragma unroll
          for (int rt=0;rt<4;rt++)
            acc[ot][rt] = mfma16(bf[ot], af[rt], acc[ot][rt]);
      }
      __builtin_amdgcn_s_setprio(0);
      __builtin_amdgcn_s_barrier();
    }
  }

  const int cout = HASV ? (cb + chalf) : (cb + mat*128 + chalf);
  if (!isV){
    #pragma unroll
    for (int ot=0;ot<4;ot++){
      const int o = cout + ot*16 + lr;
      const float bb = b1[o];
      #pragma unroll
      for (int rt=0;rt<4;rt++){
        #pragma unroll
        for (int rr=0;rr<4;rr++){
          const int r = r0 + rt*16 + lq*4 + rr;
          float bias = bb;
          if (HASV) bias += pos1[((r % K_K)/980)*C_C + o];
          outK[(size_t)r*C_C + o] = f2b(acc[rt][ot][rr] + bias);
        }
      }
    }
  } else {
    #pragma unroll
    for (int ot=0;ot<4;ot++){
      #pragma unroll
      for (int rr=0;rr<4;rr++){
        const int o = cout + ot*16 + lq*4 + rr;
        const float bb = b2[o];
        #pragma unroll
        for (int rt=0;rt<4;rt++){
          const int r = r0 + rt*16 + lr;
          const int n = r / K_K;
          const int rn = r - n*K_K;
          const float bias = bb + pos2[(rn/980)*C_C + o];
          outVT[(size_t)n*C_C*K_P + (size_t)o*K_P + rn] = f2b(acc[ot][rt][rr] + bias);
        }
      }
    }
  }
}

// ---------------------------------------------------------------------------
// Scores + fused exp/row-sum (r12, unchanged). 512 threads, 128x256, BK=32.
// ---------------------------------------------------------------------------
__global__ __launch_bounds__(512, 2) void k_scores(
    const unsigned short* __restrict__ A, const unsigned short* __restrict__ B,
    unsigned short* __restrict__ out16, float* __restrict__ rowsum)
{
  const int tid = threadIdx.x, wid = tid>>6, lane = tid&63;
  const int lr = lane&15, lq = lane>>4;
  const int wr = wid>>2, wc = wid&3;

  int x = blockIdx.x & 7, idx = blockIdx.x >> 3;
  int w = x*128 + idx;
  const int nslab = w >> 5; int sub = w & 31;
  const int ctsel = sub & 15, rtile = sub >> 4;
  const int r0 = rtile*128;
  const unsigned short* Aslab = A + (size_t)nslab*S_S*C_C;
  const unsigned short* Bslab = B + (size_t)nslab*K_K*C_C + (size_t)ctsel*256*512;

  __shared__ unsigned short SA[2][4096];
  __shared__ unsigned short SB[2][8192];

  f4v acc[4][4];
  #pragma unroll
  for (int i=0;i<4;i++)
    #pragma unroll
    for (int j=0;j<4;j++) acc[i][j]=(f4v){0,0,0,0};

  const int rsub = lane >> 2;
  const int csub = ((lane & 3) ^ ((rsub>>1)&3)) * 8;

  auto STAGE = [&](int buf, int c0){
    GLOAD16(Aslab + (size_t)(r0 + wid*16 + rsub)*512 + c0 + csub,
            &SA[buf][(wid*16)*32]);
    GLOAD16(Bslab + (size_t)(wid*16 + rsub)*512 + c0 + csub,
            &SB[buf][(wid*16)*32]);
    GLOAD16(Bslab + (size_t)(128 + wid*16 + rsub)*512 + c0 + csub,
            &SB[buf][(128 + wid*16)*32]);
  };

  STAGE(0, 0);

  const int rchunk = (lq ^ ((lr>>1)&3)) * 8;
  for (int it = 0; it < 16; ++it){
    const int buf = it & 1;
    if (it < 15){
      STAGE(buf^1, (it+1)*32);
      asm volatile("s_waitcnt vmcnt(3)" ::: "memory");
    } else {
      asm volatile("s_waitcnt vmcnt(0)" ::: "memory");
    }
    __builtin_amdgcn_s_barrier();
    s8v af[4], bf[4];
    #pragma unroll
    for (int i=0;i<4;i++)
      af[i] = *(const s8v*)&SA[buf][(wr*64 + i*16 + lr)*32 + rchunk];
    #pragma unroll
    for (int j=0;j<4;j++)
      bf[j] = *(const s8v*)&SB[buf][(wc*64 + j*16 + lr)*32 + rchunk];
    #pragma unroll
    for (int ot=0;ot<4;ot++)
      #pragma unroll
      for (int rt=0;rt<4;rt++)
        acc[rt][ot] = mfma16(af[rt], bf[ot], acc[rt][ot]);
    __builtin_amdgcn_s_barrier();
  }

  float psum[4][4];
  #pragma unroll
  for (int rt=0;rt<4;rt++)
    #pragma unroll
    for (int rr=0;rr<4;rr++) psum[rt][rr] = 0.f;

  #pragma unroll
  for (int ot=0;ot<4;ot++){
    const int kcol = ctsel*256 + wc*64 + ot*16 + lr;
    #pragma unroll
    for (int rt=0;rt<4;rt++){
      #pragma unroll
      for (int rr=0;rr<4;rr++){
        const int s = r0 + wr*64 + rt*16 + lq*4 + rr;
        float e = (kcol < K_K) ? __expf(acc[rt][ot][rr]*SCALEF) : 0.f;
        psum[rt][rr] += e;
        if (s < S_P)
          out16[((size_t)nslab*S_P + s)*K_P + kcol] = f2b(e);
      }
    }
  }
  #pragma unroll
  for (int rt=0;rt<4;rt++){
    #pragma unroll
    for (int rr=0;rr<4;rr++){
      float v = psum[rt][rr];
      v += __shfl_xor(v, 1);
      v += __shfl_xor(v, 2);
      v += __shfl_xor(v, 4);
      v += __shfl_xor(v, 8);
      if (lr == 0){
        const int s = r0 + wr*64 + rt*16 + lq*4 + rr;
        if (s < S_P) atomicAdd(&rowsum[nslab*S_P + s], v);
      }
    }
  }
}

// ---------------------------------------------------------------------------
// PV GEMM (r12, unchanged): 256 threads, 128x128, BK=32, K-split 2, 1/rowsum
// applied in epilogue; f32 partial slabs. grid 512 = 8*64.
// ---------------------------------------------------------------------------
__global__ __launch_bounds__(256, 2) void k_pv(
    const unsigned short* __restrict__ A, const unsigned short* __restrict__ B,
    const float* __restrict__ rowsum, float* __restrict__ out32)
{
  const int tid = threadIdx.x, wid = tid>>6, lane = tid&63;
  const int lr = lane&15, lq = lane>>4;
  const int wr = wid>>1, wc = wid&1;

  int x = blockIdx.x & 7, idx = blockIdx.x >> 3;
  int w = x*64 + idx;
  const int nslab = w >> 4; int sub = w & 15;
  const int ks = sub >> 3, rtile = (sub>>2)&1, ctsel = sub & 3;
  const int r0 = rtile*128;
  const int koff = ks*2048;
  const unsigned short* Aslab = A + (size_t)nslab*S_P*K_P;
  const unsigned short* Bslab = B + (size_t)nslab*C_C*K_P + (size_t)ctsel*128*K_P;

  __shared__ unsigned short SA[2][4096];
  __shared__ unsigned short SB[2][4096];

  f4v acc[4][4];
  #pragma unroll
  for (int i=0;i<4;i++)
    #pragma unroll
    for (int j=0;j<4;j++) acc[i][j]=(f4v){0,0,0,0};

  const int rsub = lane >> 2;
  const int csub = ((lane & 3) ^ ((rsub>>1)&3)) * 8;

  auto STAGE = [&](int buf, int c0){
    GLOAD16(Aslab + (size_t)(r0 + wid*16 + rsub)*K_P + c0 + csub,
            &SA[buf][(wid*16)*32]);
    GLOAD16(Aslab + (size_t)(r0 + 64 + wid*16 + rsub)*K_P + c0 + csub,
            &SA[buf][(64 + wid*16)*32]);
    GLOAD16(Bslab + (size_t)(wid*16 + rsub)*K_P + c0 + csub,
            &SB[buf][(wid*16)*32]);
    GLOAD16(Bslab + (size_t)(64 + wid*16 + rsub)*K_P + c0 + csub,
            &SB[buf][(64 + wid*16)*32]);
  };

  STAGE(0, koff);

  const int rchunk = (lq ^ ((lr>>1)&3)) * 8;
  for (int it = 0; it < 64; ++it){
    const int buf = it & 1;
    if (it < 63){
      STAGE(buf^1, koff + (it+1)*32);
      asm volatile("s_waitcnt vmcnt(4)" ::: "memory");
    } else {
      asm volatile("s_waitcnt vmcnt(0)" ::: "memory");
    }
    __builtin_amdgcn_s_barrier();
    s8v af[4], bf[4];
    #pragma unroll
    for (int i=0;i<4;i++)
      af[i] = *(const s8v*)&SA[buf][(wr*64 + i*16 + lr)*32 + rchunk];
    #pragma unroll
    for (int j=0;j<4;j++)
      bf[j] = *(const s8v*)&SB[buf][(wc*64 + j*16 + lr)*32 + rchunk];
    #pragma unroll
    for (int ot=0;ot<4;ot++)
      #pragma unroll
      for (int rt=0;rt<4;rt++)
        acc[rt][ot] = mfma16(af[rt], bf[ot], acc[rt][ot]);
    __builtin_amdgcn_s_barrier();
  }

  float invs[4][4];
  #pragma unroll
  for (int rt=0;rt<4;rt++){
    #pragma unroll
    for (int rr=0;rr<4;rr++){
      const int s = r0 + wr*64 + rt*16 + lq*4 + rr;
      invs[rt][rr] = (s < S_P) ? 1.f/rowsum[(size_t)nslab*S_P + s] : 0.f;
    }
  }
  float* op = out32 + (size_t)ks*(N_B*S_P*C_C);
  #pragma unroll
  for (int ot=0;ot<4;ot++){
    const int c = ctsel*128 + wc*64 + ot*16 + lr;
    #pragma unroll
    for (int rt=0;rt<4;rt++){
      #pragma unroll
      for (int rr=0;rr<4;rr++){
        const int s = r0 + wr*64 + rt*16 + lq*4 + rr;
        if (s < S_P)
          op[((size_t)nslab*S_P + s)*C_C + c] = acc[rt][ot][rr]*invs[rt][rr];
      }
    }
  }
}

__global__ void k_lnpart(const float* __restrict__ O0, const float* __restrict__ O1,
                         float* __restrict__ sums){
  const int part = blockIdx.x, n = blockIdx.y;
  const int tid = threadIdx.x;
  const size_t base = ((size_t)n*S_P + part*49)*C_C;
  float ls=0.f, ls2=0.f;
  for (int i = tid; i < 49*C_C/4; i += 256){
    f4v a = ((const f4v*)(O0+base))[i];
    f4v b = ((const f4v*)(O1+base))[i];
    #pragma unroll
    for (int j=0;j<4;j++){ float v = a[j]+b[j]; ls += v; ls2 += v*v; }
  }
  #pragma unroll
  for (int d=32;d>=1;d>>=1){ ls += __shfl_xor(ls,d); ls2 += __shfl_xor(ls2,d); }
  __shared__ float r1[4], r2[4];
  if ((tid&63)==0){ r1[tid>>6]=ls; r2[tid>>6]=ls2; }
  __syncthreads();
  if (tid==0){
    atomicAdd(&sums[n*2],   r1[0]+r1[1]+r1[2]+r1[3]);
    atomicAdd(&sums[n*2+1], r2[0]+r2[1]+r2[2]+r2[3]);
  }
}

__global__ void k_norm(const float* __restrict__ O0, const float* __restrict__ O1,
                       const float* __restrict__ sums, unsigned short* __restrict__ ob){
  size_t g = (size_t)blockIdx.x*256 + threadIdx.x;
  int n = (int)(g / (S_P*C_C/8));
  int rem = (int)(g - (size_t)n*(S_P*C_C/8));
  int s = rem / (C_C/8);
  const float inv = 1.f/((float)S_S*C_C);
  float mu = sums[n*2]*inv;
  float var = sums[n*2+1]*inv - mu*mu;
  float rq = rsqrtf(var + 1e-5f);
  const f4v* s0 = (const f4v*)(O0 + g*8);
  const f4v* s1 = (const f4v*)(O1 + g*8);
  f4v a0 = s0[0], a1 = s0[1], b0 = s1[0], b1 = s1[1];
  unsigned short o16[8];
  if (s < S_S){
    #pragma unroll
    for (int i=0;i<4;i++){ float y=(a0[i]+b0[i]-mu)*rq; o16[i]=f2b(fmaxf(y,0.f)); }
    #pragma unroll
    for (int i=0;i<4;i++){ float y=(a1[i]+b1[i]-mu)*rq; o16[4+i]=f2b(fmaxf(y,0.f)); }
  } else {
    #pragma unroll
    for (int i=0;i<8;i++) o16[i]=0;
  }
  *(s8v*)(ob + g*8) = *(const s8v*)o16;
}

__global__ __launch_bounds__(256) void k_final(const unsigned short* __restrict__ ob,
    const unsigned short* __restrict__ Wo, const float* __restrict__ bo,
    const float* __restrict__ person, float* __restrict__ out)
{
  const int ocb = blockIdx.x, n = blockIdx.y;
  const int tid=threadIdx.x, wid=tid>>6, lane=tid&63, lr=lane&15, lq=lane>>4;
  const int ocb0 = ocb*64 + wid*16;
  const unsigned short* obp = ob + (size_t)n*S_P*C_C;
  f4v acc[13];
  #pragma unroll
  for (int i=0;i<13;i++) acc[i]=(f4v){0,0,0,0};
  for (int c0=0;c0<C_C;c0+=32){
    s8v af = *(const s8v*)(Wo + (size_t)(ocb0+lr)*C_C + c0 + lq*8);
    #pragma unroll
    for (int ct=0;ct<13;ct++){
      s8v bfv = *(const s8v*)(obp + (size_t)(ct*16+lr)*C_C + c0 + lq*8);
      acc[ct]=mfma16(af,bfv,acc[ct]);
    }
  }
  #pragma unroll
  for (int ct=0;ct<13;ct++){
    #pragma unroll
    for (int r=0;r<4;r++){
      int oc = ocb0 + lq*4 + r;
      int s = ct*16 + lr;
      if (s < S_S){
        size_t idx = ((size_t)n*C_C + oc)*S_S + s;
        out[idx] = acc[ct][r] + bo[oc] + person[idx];
      }
    }
  }
}

extern "C" void kernel_launch(void* const* d_in, const int* in_sizes, int n_in,
                              void* d_out, int out_size, void* d_ws, size_t ws_size,
                              hipStream_t stream)
{
  (void)in_sizes; (void)n_in; (void)out_size;
  const float* person = (const float*)d_in[0];
  const float* others = (const float*)d_in[1];
  const float* Wq = (const float*)d_in[2];
  const float* bq = (const float*)d_in[3];
  const float* Wk = (const float*)d_in[4];
  const float* bk = (const float*)d_in[5];
  const float* Wv = (const float*)d_in[6];
  const float* bv = (const float*)d_in[7];
  const float* Wo = (const float*)d_in[8];
  const float* bo = (const float*)d_in[9];
  const float* pos_k = (const float*)d_in[10];
  const float* pos_v = (const float*)d_in[11];
  float* out = (float*)d_out;

  char* ws = (char*)d_ws;
  size_t off = 0;
  auto alloc = [&](size_t bytes)->char*{
    char* p = ws + off; off += (bytes + 255) & ~(size_t)255; return p;
  };
  unsigned short* Wb  = (unsigned short*)alloc(4ull*C_C*C_C*2);
  unsigned short* Xt  = (unsigned short*)alloc(((size_t)N_B*M_O*S_S + 16)*C_C*2);
  unsigned short* Qt  = (unsigned short*)alloc(((size_t)N_B*S_S + 16)*C_C*2);
  unsigned short* qb  = (unsigned short*)alloc(((size_t)N_B*S_S + 64)*C_C*2);
  unsigned short* kfb = (unsigned short*)alloc(((size_t)N_B*K_K + 256)*C_C*2);
  unsigned short* vtb = (unsigned short*)alloc((size_t)N_B*C_C*K_P*2);
  unsigned short* Sbuf= (unsigned short*)alloc(((size_t)N_B*S_P + 64)*K_P*2);
  float* sums         = (float*)alloc(2*N_B*sizeof(float));
  float* rowsum       = (float*)alloc((size_t)N_B*S_P*sizeof(float));

  // Alias Obuf (f32, 2 K-split halves) + obb into the dead Xt/Qt/qb region
  // after k_scores (k_pv reads only Sbuf/vtb/rowsum).
  float* Obuf         = (float*)Xt;
  unsigned short* obb = (unsigned short*)((char*)Xt +
                          ((2ull*N_B*S_P*C_C*4 + 255) & ~(size_t)255));

  if (off > ws_size) {
    k_sentinel<<<1,256,0,stream>>>(out, (float)(ws_size>>20));
    return;
  }

  unsigned short* Wq_b = Wb;
  unsigned short* Wk_b = Wb + 262144;
  unsigned short* Wv_b = Wb + 2*262144;
  unsigned short* Wo_b = Wb + 3*262144;
  float* O1 = Obuf + (size_t)N_B*S_P*C_C;

  hipMemsetAsync(sums, 0, 2*N_B*sizeof(float), stream);
  hipMemsetAsync(rowsum, 0, (size_t)N_B*S_P*sizeof(float), stream);
  k_cvt<<<1024,256,0,stream>>>(Wq,Wk,Wv,Wo,Wb);
  k_tr<<<dim3(8,N_B*M_O),256,0,stream>>>(others, Xt);
  k_tr<<<dim3(8,N_B),256,0,stream>>>(person, Qt);
  k_projgemm<true ><<<7840,256,0,stream>>>(Xt,
      Wk_b, bk, pos_k, Wv_b, bv, pos_v, kfb, vtb);
  k_projgemm<false><<<196,256,0,stream>>>(Qt,
      Wq_b, bq, nullptr, nullptr, nullptr, nullptr, qb, nullptr);
  k_scores<<<1024,512,0,stream>>>(qb, kfb, Sbuf, rowsum);
  k_pv<<<512,256,0,stream>>>(Sbuf, vtb, rowsum, Obuf);
  k_lnpart<<<dim3(4,N_B),256,0,stream>>>(Obuf, O1, sums);
  k_norm<<<1664,256,0,stream>>>(Obuf, O1, sums, obb);
  k_final<<<dim3(8,N_B),256,0,stream>>>(obb, Wo_b, bo, person, out);
}

// Round 19
// 571.315 us; speedup vs baseline: 1.0175x; 1.0175x over previous
//
#include <hip/hip_runtime.h>
#include <hip/hip_bf16.h>

#define N_B 32
#define M_O 20
#define C_C 512
#define S_S 196
#define S_P 208
#define K_K 3920
#define K_P 4096
#define SCALEF 0.044194173824159216f  // 1/sqrt(512)

typedef short s4v __attribute__((ext_vector_type(4)));
typedef short s8v __attribute__((ext_vector_type(8)));
typedef float f4v __attribute__((ext_vector_type(4)));

__device__ __forceinline__ f4v mfma16(s8v a, s8v b, f4v c){
  return __builtin_amdgcn_mfma_f32_16x16x32_bf16(a, b, c, 0, 0, 0);
}
__device__ __forceinline__ unsigned short f2b(float x){
  __hip_bfloat16 h = __float2bfloat16(x);
  return *reinterpret_cast<unsigned short*>(&h);
}
__device__ __forceinline__ float b2f(short u){
  unsigned int v = ((unsigned int)(unsigned short)u) << 16;
  return __uint_as_float(v);
}

#define GLOAD16(g, l) __builtin_amdgcn_global_load_lds( \
    (const __attribute__((address_space(1))) unsigned int*)(g), \
    (__attribute__((address_space(3))) unsigned int*)(l), 16, 0, 0)

__global__ void k_sentinel(float* out, float v){ out[threadIdx.x] = v; }

__global__ void k_cvt(const float* __restrict__ w0, const float* __restrict__ w1,
                      const float* __restrict__ w2, const float* __restrict__ w3,
                      unsigned short* __restrict__ out){
  int i = blockIdx.x*256 + threadIdx.x;
  int m = i >> 16;
  int r = i & 65535;
  const float* s = (m==0)?w0:((m==1)?w1:((m==2)?w2:w3));
  f4v v = ((const f4v*)s)[r];
  s4v o = { (short)f2b(v[0]), (short)f2b(v[1]), (short)f2b(v[2]), (short)f2b(v[3]) };
  ((s4v*)out)[i] = o;
}

// Transpose+cvt: X fp32 [slab][512][196] -> Xt bf16 [slab][196][512]
__global__ __launch_bounds__(256) void k_tr(const float* __restrict__ X,
                                            unsigned short* __restrict__ Xt){
  const int cc = blockIdx.x * 64;
  const int slab = blockIdx.y;
  const int tid = threadIdx.x;
  __shared__ unsigned short A[196][72];
  const int row = tid >> 2;
  const int j   = tid & 3;
  const float* src = X + (size_t)slab*(C_C*S_S) + (size_t)(cc+row)*S_S;
  for (int p = j; p < 49; p += 4){
    f4v v = *(const f4v*)(src + p*4);
    int s = p*4;
    A[s+0][row] = f2b(v[0]);
    A[s+1][row] = f2b(v[1]);
    A[s+2][row] = f2b(v[2]);
    A[s+3][row] = f2b(v[3]);
  }
  __syncthreads();
  unsigned short* dst = Xt + (size_t)slab*(S_S*C_C) + cc;
  for (int v = tid; v < S_S*8; v += 256){
    int s = v >> 3, c8 = v & 7;
    *(s8v*)(dst + (size_t)s*C_C + c8*8) = *(const s8v*)&A[s][c8*8];
  }
}

// ---------------------------------------------------------------------------
// Projection GEMM, T3/T4/T5 phased schedule (r17 exact — best measured).
// BK=64 = 2 phases/step of 16 MFMA; per phase: ds_read half h || issue
// next-step gloads(h) -> counted vmcnt(5) (never 0 mid-loop) -> barrier ->
// lgkmcnt(0)+sched_barrier (pin: early ds_reads drain under barrier wait) ->
// setprio(1) MFMA setprio(0) -> barrier.
// 256 threads = 4 waves, tile 64x256, contiguous-64B staging + T2 swizzle.
// Waves 0-1: K output; waves 2-3: V output (swapped-operand, transposed store).
// ---------------------------------------------------------------------------
template<bool HASV>
__global__ __launch_bounds__(256, 2) void k_projgemm(
    const unsigned short* __restrict__ Xt,
    const unsigned short* __restrict__ W1, const float* __restrict__ b1, const float* __restrict__ pos1,
    const unsigned short* __restrict__ W2, const float* __restrict__ b2, const float* __restrict__ pos2,
    unsigned short* __restrict__ outK, unsigned short* __restrict__ outVT)
{
  const int id = blockIdx.x;
  const int work = HASV ? ((id & 7)*980 + (id >> 3)) : id;
  const int ct    = HASV ? (work & 3) : (work & 1);
  const int rtile = HASV ? (work >> 2) : (work >> 1);
  const int r0 = rtile*64;
  const int cb = ct * (HASV ? 128 : 256);
  const int tid = threadIdx.x, wid = tid>>6, lane = tid&63;
  const int lr = lane&15, lq = lane>>4;
  const int mat = wid >> 1, chalf = (wid & 1)*64;
  const bool isV = HASV && (mat == 1);

  const unsigned short* WB = HASV ? W2 : W1;
  const int cbB = HASV ? cb : cb + 128;

  __shared__ unsigned short SA[2][2][2048];   // [buf][h][row*32+c] 64x32
  __shared__ unsigned short SB[2][2][8192];   // [buf][h][brow*32+c] 256x32

  f4v acc[4][4];
  #pragma unroll
  for (int i=0;i<4;i++)
    #pragma unroll
    for (int j=0;j<4;j++) acc[i][j]=(f4v){0,0,0,0};

  const int rsub = lane >> 2;
  const int csub = ((lane & 3) ^ ((rsub>>1)&3)) * 8;

  auto STAGE = [&](int buf, int h, int c0){
    const unsigned short* ga = Xt + (size_t)(r0 + wid*16 + rsub)*C_C + c0 + h*32 + csub;
    GLOAD16(ga, &SA[buf][h][(wid*16)*32]);
    #pragma unroll
    for (int j=0;j<4;j++){
      const int br = j*64 + wid*16 + rsub;
      const unsigned short* gw = (j<2)
        ? W1 + (size_t)(cb  + br      )*C_C + c0 + h*32 + csub
        : WB + (size_t)(cbB + br - 128)*C_C + c0 + h*32 + csub;
      GLOAD16(gw, &SB[buf][h][(j*64 + wid*16)*32]);
    }
  };

  STAGE(0, 0, 0);
  STAGE(0, 1, 0);
  asm volatile("s_waitcnt vmcnt(5)" ::: "memory");   // (0,0) ready; (0,1) in flight
  __builtin_amdgcn_s_barrier();

  const int bbase = mat*128 + chalf;
  const int rchunk = (lq ^ ((lr>>1)&3)) * 8;
  for (int it = 0; it < 8; ++it){
    const int buf = it & 1;
    #pragma unroll
    for (int h = 0; h < 2; ++h){
      s8v af[4], bf[4];
      #pragma unroll
      for (int i=0;i<4;i++)
        af[i] = *(const s8v*)&SA[buf][h][(i*16 + lr)*32 + rchunk];
      #pragma unroll
      for (int i=0;i<4;i++)
        bf[i] = *(const s8v*)&SB[buf][h][(bbase + i*16 + lr)*32 + rchunk];
      if (it < 7){
        STAGE(buf^1, h, (it+1)*64);
        asm volatile("s_waitcnt vmcnt(5)" ::: "memory");
      } else {
        asm volatile("s_waitcnt vmcnt(0)" ::: "memory");
      }
      __builtin_amdgcn_s_barrier();
      asm volatile("s_waitcnt lgkmcnt(0)" ::: "memory");
      __builtin_amdgcn_sched_barrier(0);
      __builtin_amdgcn_s_setprio(1);
      if (!isV){
        #pragma unroll
        for (int ot=0;ot<4;ot++)
          #pragma unroll
          for (int rt=0;rt<4;rt++)
            acc[rt][ot] = mfma16(af[rt], bf[ot], acc[rt][ot]);
      } else {
        #pragma unroll
        for (int ot=0;ot<4;ot++)
          #pragma unroll
          for (int rt=0;rt<4;rt++)
            acc[ot][rt] = mfma16(bf[ot], af[rt], acc[ot][rt]);
      }
      __builtin_amdgcn_s_setprio(0);
      __builtin_amdgcn_s_barrier();
    }
  }

  const int cout = HASV ? (cb + chalf) : (cb + mat*128 + chalf);
  if (!isV){
    #pragma unroll
    for (int ot=0;ot<4;ot++){
      const int o = cout + ot*16 + lr;
      const float bb = b1[o];
      #pragma unroll
      for (int rt=0;rt<4;rt++){
        #pragma unroll
        for (int rr=0;rr<4;rr++){
          const int r = r0 + rt*16 + lq*4 + rr;
          float bias = bb;
          if (HASV) bias += pos1[((r % K_K)/980)*C_C + o];
          outK[(size_t)r*C_C + o] = f2b(acc[rt][ot][rr] + bias);
        }
      }
    }
  } else {
    #pragma unroll
    for (int ot=0;ot<4;ot++){
      #pragma unroll
      for (int rr=0;rr<4;rr++){
        const int o = cout + ot*16 + lq*4 + rr;
        const float bb = b2[o];
        #pragma unroll
        for (int rt=0;rt<4;rt++){
          const int r = r0 + rt*16 + lr;
          const int n = r / K_K;
          const int rn = r - n*K_K;
          const float bias = bb + pos2[(rn/980)*C_C + o];
          outVT[(size_t)n*C_C*K_P + (size_t)o*K_P + rn] = f2b(acc[ot][rt][rr] + bias);
        }
      }
    }
  }
}

// ---------------------------------------------------------------------------
// Scores + fused exp/row-sum (r12, unchanged). 512 threads, 128x256, BK=32.
// ---------------------------------------------------------------------------
__global__ __launch_bounds__(512, 2) void k_scores(
    const unsigned short* __restrict__ A, const unsigned short* __restrict__ B,
    unsigned short* __restrict__ out16, float* __restrict__ rowsum)
{
  const int tid = threadIdx.x, wid = tid>>6, lane = tid&63;
  const int lr = lane&15, lq = lane>>4;
  const int wr = wid>>2, wc = wid&3;

  int x = blockIdx.x & 7, idx = blockIdx.x >> 3;
  int w = x*128 + idx;
  const int nslab = w >> 5; int sub = w & 31;
  const int ctsel = sub & 15, rtile = sub >> 4;
  const int r0 = rtile*128;
  const unsigned short* Aslab = A + (size_t)nslab*S_S*C_C;
  const unsigned short* Bslab = B + (size_t)nslab*K_K*C_C + (size_t)ctsel*256*512;

  __shared__ unsigned short SA[2][4096];
  __shared__ unsigned short SB[2][8192];

  f4v acc[4][4];
  #pragma unroll
  for (int i=0;i<4;i++)
    #pragma unroll
    for (int j=0;j<4;j++) acc[i][j]=(f4v){0,0,0,0};

  const int rsub = lane >> 2;
  const int csub = ((lane & 3) ^ ((rsub>>1)&3)) * 8;

  auto STAGE = [&](int buf, int c0){
    GLOAD16(Aslab + (size_t)(r0 + wid*16 + rsub)*512 + c0 + csub,
            &SA[buf][(wid*16)*32]);
    GLOAD16(Bslab + (size_t)(wid*16 + rsub)*512 + c0 + csub,
            &SB[buf][(wid*16)*32]);
    GLOAD16(Bslab + (size_t)(128 + wid*16 + rsub)*512 + c0 + csub,
            &SB[buf][(128 + wid*16)*32]);
  };

  STAGE(0, 0);

  const int rchunk = (lq ^ ((lr>>1)&3)) * 8;
  for (int it = 0; it < 16; ++it){
    const int buf = it & 1;
    if (it < 15){
      STAGE(buf^1, (it+1)*32);
      asm volatile("s_waitcnt vmcnt(3)" ::: "memory");
    } else {
      asm volatile("s_waitcnt vmcnt(0)" ::: "memory");
    }
    __builtin_amdgcn_s_barrier();
    s8v af[4], bf[4];
    #pragma unroll
    for (int i=0;i<4;i++)
      af[i] = *(const s8v*)&SA[buf][(wr*64 + i*16 + lr)*32 + rchunk];
    #pragma unroll
    for (int j=0;j<4;j++)
      bf[j] = *(const s8v*)&SB[buf][(wc*64 + j*16 + lr)*32 + rchunk];
    #pragma unroll
    for (int ot=0;ot<4;ot++)
      #pragma unroll
      for (int rt=0;rt<4;rt++)
        acc[rt][ot] = mfma16(af[rt], bf[ot], acc[rt][ot]);
    __builtin_amdgcn_s_barrier();
  }

  float psum[4][4];
  #pragma unroll
  for (int rt=0;rt<4;rt++)
    #pragma unroll
    for (int rr=0;rr<4;rr++) psum[rt][rr] = 0.f;

  #pragma unroll
  for (int ot=0;ot<4;ot++){
    const int kcol = ctsel*256 + wc*64 + ot*16 + lr;
    #pragma unroll
    for (int rt=0;rt<4;rt++){
      #pragma unroll
      for (int rr=0;rr<4;rr++){
        const int s = r0 + wr*64 + rt*16 + lq*4 + rr;
        float e = (kcol < K_K) ? __expf(acc[rt][ot][rr]*SCALEF) : 0.f;
        psum[rt][rr] += e;
        if (s < S_P)
          out16[((size_t)nslab*S_P + s)*K_P + kcol] = f2b(e);
      }
    }
  }
  #pragma unroll
  for (int rt=0;rt<4;rt++){
    #pragma unroll
    for (int rr=0;rr<4;rr++){
      float v = psum[rt][rr];
      v += __shfl_xor(v, 1);
      v += __shfl_xor(v, 2);
      v += __shfl_xor(v, 4);
      v += __shfl_xor(v, 8);
      if (lr == 0){
        const int s = r0 + wr*64 + rt*16 + lq*4 + rr;
        if (s < S_P) atomicAdd(&rowsum[nslab*S_P + s], v);
      }
    }
  }
}

// ---------------------------------------------------------------------------
// PV GEMM (r12, unchanged): 256 threads, 128x128, BK=32, K-split 2, 1/rowsum
// applied in epilogue; f32 partial slabs. grid 512 = 8*64.
// ---------------------------------------------------------------------------
__global__ __launch_bounds__(256, 2) void k_pv(
    const unsigned short* __restrict__ A, const unsigned short* __restrict__ B,
    const float* __restrict__ rowsum, float* __restrict__ out32)
{
  const int tid = threadIdx.x, wid = tid>>6, lane = tid&63;
  const int lr = lane&15, lq = lane>>4;
  const int wr = wid>>1, wc = wid&1;

  int x = blockIdx.x & 7, idx = blockIdx.x >> 3;
  int w = x*64 + idx;
  const int nslab = w >> 4; int sub = w & 15;
  const int ks = sub >> 3, rtile = (sub>>2)&1, ctsel = sub & 3;
  const int r0 = rtile*128;
  const int koff = ks*2048;
  const unsigned short* Aslab = A + (size_t)nslab*S_P*K_P;
  const unsigned short* Bslab = B + (size_t)nslab*C_C*K_P + (size_t)ctsel*128*K_P;

  __shared__ unsigned short SA[2][4096];
  __shared__ unsigned short SB[2][4096];

  f4v acc[4][4];
  #pragma unroll
  for (int i=0;i<4;i++)
    #pragma unroll
    for (int j=0;j<4;j++) acc[i][j]=(f4v){0,0,0,0};

  const int rsub = lane >> 2;
  const int csub = ((lane & 3) ^ ((rsub>>1)&3)) * 8;

  auto STAGE = [&](int buf, int c0){
    GLOAD16(Aslab + (size_t)(r0 + wid*16 + rsub)*K_P + c0 + csub,
            &SA[buf][(wid*16)*32]);
    GLOAD16(Aslab + (size_t)(r0 + 64 + wid*16 + rsub)*K_P + c0 + csub,
            &SA[buf][(64 + wid*16)*32]);
    GLOAD16(Bslab + (size_t)(wid*16 + rsub)*K_P + c0 + csub,
            &SB[buf][(wid*16)*32]);
    GLOAD16(Bslab + (size_t)(64 + wid*16 + rsub)*K_P + c0 + csub,
            &SB[buf][(64 + wid*16)*32]);
  };

  STAGE(0, koff);

  const int rchunk = (lq ^ ((lr>>1)&3)) * 8;
  for (int it = 0; it < 64; ++it){
    const int buf = it & 1;
    if (it < 63){
      STAGE(buf^1, koff + (it+1)*32);
      asm volatile("s_waitcnt vmcnt(4)" ::: "memory");
    } else {
      asm volatile("s_waitcnt vmcnt(0)" ::: "memory");
    }
    __builtin_amdgcn_s_barrier();
    s8v af[4], bf[4];
    #pragma unroll
    for (int i=0;i<4;i++)
      af[i] = *(const s8v*)&SA[buf][(wr*64 + i*16 + lr)*32 + rchunk];
    #pragma unroll
    for (int j=0;j<4;j++)
      bf[j] = *(const s8v*)&SB[buf][(wc*64 + j*16 + lr)*32 + rchunk];
    #pragma unroll
    for (int ot=0;ot<4;ot++)
      #pragma unroll
      for (int rt=0;rt<4;rt++)
        acc[rt][ot] = mfma16(af[rt], bf[ot], acc[rt][ot]);
    __builtin_amdgcn_s_barrier();
  }

  float invs[4][4];
  #pragma unroll
  for (int rt=0;rt<4;rt++){
    #pragma unroll
    for (int rr=0;rr<4;rr++){
      const int s = r0 + wr*64 + rt*16 + lq*4 + rr;
      invs[rt][rr] = (s < S_P) ? 1.f/rowsum[(size_t)nslab*S_P + s] : 0.f;
    }
  }
  float* op = out32 + (size_t)ks*(N_B*S_P*C_C);
  #pragma unroll
  for (int ot=0;ot<4;ot++){
    const int c = ctsel*128 + wc*64 + ot*16 + lr;
    #pragma unroll
    for (int rt=0;rt<4;rt++){
      #pragma unroll
      for (int rr=0;rr<4;rr++){
        const int s = r0 + wr*64 + rt*16 + lq*4 + rr;
        if (s < S_P)
          op[((size_t)nslab*S_P + s)*C_C + c] = acc[rt][ot][rr]*invs[rt][rr];
      }
    }
  }
}

__global__ void k_lnpart(const float* __restrict__ O0, const float* __restrict__ O1,
                         float* __restrict__ sums){
  const int part = blockIdx.x, n = blockIdx.y;
  const int tid = threadIdx.x;
  const size_t base = ((size_t)n*S_P + part*49)*C_C;
  float ls=0.f, ls2=0.f;
  for (int i = tid; i < 49*C_C/4; i += 256){
    f4v a = ((const f4v*)(O0+base))[i];
    f4v b = ((const f4v*)(O1+base))[i];
    #pragma unroll
    for (int j=0;j<4;j++){ float v = a[j]+b[j]; ls += v; ls2 += v*v; }
  }
  #pragma unroll
  for (int d=32;d>=1;d>>=1){ ls += __shfl_xor(ls,d); ls2 += __shfl_xor(ls2,d); }
  __shared__ float r1[4], r2[4];
  if ((tid&63)==0){ r1[tid>>6]=ls; r2[tid>>6]=ls2; }
  __syncthreads();
  if (tid==0){
    atomicAdd(&sums[n*2],   r1[0]+r1[1]+r1[2]+r1[3]);
    atomicAdd(&sums[n*2+1], r2[0]+r2[1]+r2[2]+r2[3]);
  }
}

__global__ void k_norm(const float* __restrict__ O0, const float* __restrict__ O1,
                       const float* __restrict__ sums, unsigned short* __restrict__ ob){
  size_t g = (size_t)blockIdx.x*256 + threadIdx.x;
  int n = (int)(g / (S_P*C_C/8));
  int rem = (int)(g - (size_t)n*(S_P*C_C/8));
  int s = rem / (C_C/8);
  const float inv = 1.f/((float)S_S*C_C);
  float mu = sums[n*2]*inv;
  float var = sums[n*2+1]*inv - mu*mu;
  float rq = rsqrtf(var + 1e-5f);
  const f4v* s0 = (const f4v*)(O0 + g*8);
  const f4v* s1 = (const f4v*)(O1 + g*8);
  f4v a0 = s0[0], a1 = s0[1], b0 = s1[0], b1 = s1[1];
  unsigned short o16[8];
  if (s < S_S){
    #pragma unroll
    for (int i=0;i<4;i++){ float y=(a0[i]+b0[i]-mu)*rq; o16[i]=f2b(fmaxf(y,0.f)); }
    #pragma unroll
    for (int i=0;i<4;i++){ float y=(a1[i]+b1[i]-mu)*rq; o16[4+i]=f2b(fmaxf(y,0.f)); }
  } else {
    #pragma unroll
    for (int i=0;i<8;i++) o16[i]=0;
  }
  *(s8v*)(ob + g*8) = *(const s8v*)o16;
}

__global__ __launch_bounds__(256) void k_final(const unsigned short* __restrict__ ob,
    const unsigned short* __restrict__ Wo, const float* __restrict__ bo,
    const float* __restrict__ person, float* __restrict__ out)
{
  const int ocb = blockIdx.x, n = blockIdx.y;
  const int tid=threadIdx.x, wid=tid>>6, lane=tid&63, lr=lane&15, lq=lane>>4;
  const int ocb0 = ocb*64 + wid*16;
  const unsigned short* obp = ob + (size_t)n*S_P*C_C;
  f4v acc[13];
  #pragma unroll
  for (int i=0;i<13;i++) acc[i]=(f4v){0,0,0,0};
  for (int c0=0;c0<C_C;c0+=32){
    s8v af = *(const s8v*)(Wo + (size_t)(ocb0+lr)*C_C + c0 + lq*8);
    #pragma unroll
    for (int ct=0;ct<13;ct++){
      s8v bfv = *(const s8v*)(obp + (size_t)(ct*16+lr)*C_C + c0 + lq*8);
      acc[ct]=mfma16(af,bfv,acc[ct]);
    }
  }
  #pragma unroll
  for (int ct=0;ct<13;ct++){
    #pragma unroll
    for (int r=0;r<4;r++){
      int oc = ocb0 + lq*4 + r;
      int s = ct*16 + lr;
      if (s < S_S){
        size_t idx = ((size_t)n*C_C + oc)*S_S + s;
        out[idx] = acc[ct][r] + bo[oc] + person[idx];
      }
    }
  }
}

extern "C" void kernel_launch(void* const* d_in, const int* in_sizes, int n_in,
                              void* d_out, int out_size, void* d_ws, size_t ws_size,
                              hipStream_t stream)
{
  (void)in_sizes; (void)n_in; (void)out_size;
  const float* person = (const float*)d_in[0];
  const float* others = (const float*)d_in[1];
  const float* Wq = (const float*)d_in[2];
  const float* bq = (const float*)d_in[3];
  const float* Wk = (const float*)d_in[4];
  const float* bk = (const float*)d_in[5];
  const float* Wv = (const float*)d_in[6];
  const float* bv = (const float*)d_in[7];
  const float* Wo = (const float*)d_in[8];
  const float* bo = (const float*)d_in[9];
  const float* pos_k = (const float*)d_in[10];
  const float* pos_v = (const float*)d_in[11];
  float* out = (float*)d_out;

  char* ws = (char*)d_ws;
  size_t off = 0;
  auto alloc = [&](size_t bytes)->char*{
    char* p = ws + off; off += (bytes + 255) & ~(size_t)255; return p;
  };
  unsigned short* Wb  = (unsigned short*)alloc(4ull*C_C*C_C*2);
  unsigned short* Xt  = (unsigned short*)alloc(((size_t)N_B*M_O*S_S + 16)*C_C*2);
  unsigned short* Qt  = (unsigned short*)alloc(((size_t)N_B*S_S + 16)*C_C*2);
  unsigned short* qb  = (unsigned short*)alloc(((size_t)N_B*S_S + 64)*C_C*2);
  unsigned short* kfb = (unsigned short*)alloc(((size_t)N_B*K_K + 256)*C_C*2);
  unsigned short* vtb = (unsigned short*)alloc((size_t)N_B*C_C*K_P*2);
  unsigned short* Sbuf= (unsigned short*)alloc(((size_t)N_B*S_P + 64)*K_P*2);
  float* sums         = (float*)alloc(2*N_B*sizeof(float));
  float* rowsum       = (float*)alloc((size_t)N_B*S_P*sizeof(float));

  // Alias Obuf (f32, 2 K-split halves) + obb into the dead Xt/Qt/qb region
  // after k_scores (k_pv reads only Sbuf/vtb/rowsum).
  float* Obuf         = (float*)Xt;
  unsigned short* obb = (unsigned short*)((char*)Xt +
                          ((2ull*N_B*S_P*C_C*4 + 255) & ~(size_t)255));

  if (off > ws_size) {
    k_sentinel<<<1,256,0,stream>>>(out, (float)(ws_size>>20));
    return;
  }

  unsigned short* Wq_b = Wb;
  unsigned short* Wk_b = Wb + 262144;
  unsigned short* Wv_b = Wb + 2*262144;
  unsigned short* Wo_b = Wb + 3*262144;
  float* O1 = Obuf + (size_t)N_B*S_P*C_C;

  hipMemsetAsync(sums, 0, 2*N_B*sizeof(float), stream);
  hipMemsetAsync(rowsum, 0, (size_t)N_B*S_P*sizeof(float), stream);
  k_cvt<<<1024,256,0,stream>>>(Wq,Wk,Wv,Wo,Wb);
  k_tr<<<dim3(8,N_B*M_O),256,0,stream>>>(others, Xt);
  k_tr<<<dim3(8,N_B),256,0,stream>>>(person, Qt);
  k_projgemm<true ><<<7840,256,0,stream>>>(Xt,
      Wk_b, bk, pos_k, Wv_b, bv, pos_v, kfb, vtb);
  k_projgemm<false><<<196,256,0,stream>>>(Qt,
      Wq_b, bq, nullptr, nullptr, nullptr, nullptr, qb, nullptr);
  k_scores<<<1024,512,0,stream>>>(qb, kfb, Sbuf, rowsum);
  k_pv<<<512,256,0,stream>>>(Sbuf, vtb, rowsum, Obuf);
  k_lnpart<<<dim3(4,N_B),256,0,stream>>>(Obuf, O1, sums);
  k_norm<<<1664,256,0,stream>>>(Obuf, O1, sums, obb);
  k_final<<<dim3(8,N_B),256,0,stream>>>(obb, Wo_b, bo, person, out);
}